// Round 1
// baseline (125.669 us; speedup 1.0000x reference)
//
#include <hip/hip_runtime.h>
#include <math.h>

#define BLOCK_KNN 256
#define MAX_N 3072   // LDS key array capacity; N=3000 in this problem

// ---------- small vector helpers ----------
__device__ __forceinline__ void cross3(const float* a, const float* b, float* o) {
    o[0] = a[1] * b[2] - a[2] * b[1];
    o[1] = a[2] * b[0] - a[0] * b[2];
    o[2] = a[0] * b[1] - a[1] * b[0];
}
__device__ __forceinline__ float dot3(const float* a, const float* b) {
    return a[0] * b[0] + a[1] * b[1] + a[2] * b[2];
}

// signed dihedral of 4 points, matches reference formula
__device__ float dihedral4(const float* a, const float* b, const float* c, const float* d) {
    float u1[3], u2[3], u3[3];
    #pragma unroll
    for (int t = 0; t < 3; t++) {
        u1[t] = b[t] - a[t];
        u2[t] = c[t] - b[t];
        u3[t] = d[t] - c[t];
    }
    float n1[3], n2[3];
    cross3(u1, u2, n1);
    cross3(u2, u3, n2);
    float nrm = sqrtf(dot3(u2, u2)) + 1e-12f;
    float u2n[3] = {u2[0] / nrm, u2[1] / nrm, u2[2] / nrm};
    float m[3];
    cross3(n1, u2n, m);
    float x = dot3(n1, n2);
    float y = dot3(m, n2);
    return atan2f(y, x);
}

// ---------- Kernel 1: node features H = [res_embed[S], sinusoid(RP)+id_embed[ID]] ----------
__global__ void node_feat_kernel(const float* __restrict__ res_embed,  // [NUM_AA, E]
                                 const float* __restrict__ id_embed,   // [NUM_ID, E]
                                 const int* __restrict__ S,
                                 const int* __restrict__ RP,
                                 const int* __restrict__ ID,
                                 float* __restrict__ H,  // [N, 2E]
                                 int N, int E) {
    int idx = blockIdx.x * blockDim.x + threadIdx.x;
    int total = N * 2 * E;
    if (idx >= total) return;
    int n = idx / (2 * E);
    int e = idx - n * (2 * E);
    float v;
    if (e < E) {
        v = res_embed[S[n] * E + e];
    } else {
        int j = e - E;
        int half = j >> 1;
        float freq = powf(10000.0f, -2.0f * (float)half / (float)E);
        float ang = (float)RP[n] * freq;
        float sc = (j & 1) ? cosf(ang) : sinf(ang);
        v = sc + id_embed[ID[n] * E + j];
    }
    H[idx] = v;
}

// ---------- Kernel 2: masked channel-pair KNN + dihedral edge attributes ----------
// one block per row i
__global__ __launch_bounds__(BLOCK_KNN) void knn_kernel(
    const float* __restrict__ X,    // [N, 4, 3]
    const int* __restrict__ Seg,
    const int* __restrict__ bid,
    float* __restrict__ out_e0,     // [N*K]  dst (neighbor) or -1, as float
    float* __restrict__ out_e1,     // [N*K]  src (row) or -1, as float
    float* __restrict__ out_attr,   // [N*K, 2] (phi, psi)
    float* __restrict__ out_valid,  // [N*K]  1/0
    int N, int K) {
    __shared__ unsigned long long keys[MAX_N];
    __shared__ unsigned long long partial[BLOCK_KNN];
    __shared__ unsigned long long winners[32];

    const int i = blockIdx.x;
    const int tid = threadIdx.x;

    // row-i atoms + squared norms (expanded-form distance matches reference)
    float xi[4][3], sqi[4];
    #pragma unroll
    for (int c = 0; c < 4; c++) {
        xi[c][0] = X[(i * 4 + c) * 3 + 0];
        xi[c][1] = X[(i * 4 + c) * 3 + 1];
        xi[c][2] = X[(i * 4 + c) * 3 + 2];
        sqi[c] = xi[c][0] * xi[c][0] + xi[c][1] * xi[c][1] + xi[c][2] * xi[c][2];
    }
    const int bi = bid[i];
    const int si = Seg[i];

    // distance pass: key = (dist_bits << 32) | j  -> argmin == (smallest dist, lowest j)
    for (int j = tid; j < N; j += BLOCK_KNN) {
        float dist;
        if (bid[j] == bi && Seg[j] == si) {
            float xj[4][3], sqj[4];
            #pragma unroll
            for (int c = 0; c < 4; c++) {
                xj[c][0] = X[(j * 4 + c) * 3 + 0];
                xj[c][1] = X[(j * 4 + c) * 3 + 1];
                xj[c][2] = X[(j * 4 + c) * 3 + 2];
                sqj[c] = xj[c][0] * xj[c][0] + xj[c][1] * xj[c][1] + xj[c][2] * xj[c][2];
            }
            float best = 3.4e38f;
            #pragma unroll
            for (int c = 0; c < 4; c++) {
                #pragma unroll
                for (int e = 0; e < 4; e++) {
                    float dp = xi[c][0] * xj[e][0] + xi[c][1] * xj[e][1] + xi[c][2] * xj[e][2];
                    float d2 = (sqi[c] + sqj[e]) - 2.0f * dp;
                    best = fminf(best, d2);
                }
            }
            dist = sqrtf(fmaxf(best, 0.0f));
        } else {
            dist = 1e10f;  // BIGINT, exact
        }
        keys[j] = ((unsigned long long)__float_as_uint(dist) << 32) | (unsigned)j;
    }
    __syncthreads();

    // K serial block-wide argmin extractions (reproduces lax.top_k ordering)
    for (int t = 0; t < K; t++) {
        unsigned long long best = ~0ull;
        for (int j = tid; j < N; j += BLOCK_KNN) {
            unsigned long long kk = keys[j];
            if (kk < best) best = kk;
        }
        partial[tid] = best;
        __syncthreads();
        #pragma unroll
        for (int s = BLOCK_KNN / 2; s > 0; s >>= 1) {
            if (tid < s) {
                unsigned long long o = partial[tid + s];
                if (o < partial[tid]) partial[tid] = o;
            }
            __syncthreads();
        }
        if (tid == 0) {
            unsigned long long w = partial[0];
            winners[t] = w;
            keys[(unsigned)(w & 0xffffffffu)] = ~0ull;  // remove winner
        }
        __syncthreads();
    }

    // emit edges + dihedrals (threads 0..K-1)
    if (tid < K) {
        unsigned long long w = winners[tid];
        float dist = __uint_as_float((unsigned)(w >> 32));
        int j = (int)(w & 0xffffffffu);
        bool valid = dist < 1e10f;
        int e = i * K + tid;

        out_e0[e] = valid ? (float)j : -1.0f;
        out_e1[e] = valid ? (float)i : -1.0f;
        out_valid[e] = valid ? 1.0f : 0.0f;

        float phi = 0.0f, psi = 0.0f;
        if (valid) {
            float xj[4][3];
            #pragma unroll
            for (int c = 0; c < 4; c++) {
                xj[c][0] = X[(j * 4 + c) * 3 + 0];
                xj[c][1] = X[(j * 4 + c) * 3 + 1];
                xj[c][2] = X[(j * 4 + c) * 3 + 2];
            }
            // phi: C_j, N_i, CA_i, C_i   (dst = neighbor j, src = row i)
            phi = dihedral4(xj[2], xi[0], xi[1], xi[2]);
            // psi: N_j, CA_j, C_j, N_i
            psi = dihedral4(xj[0], xj[1], xj[2], xi[0]);
        }
        out_attr[e * 2 + 0] = phi;
        out_attr[e * 2 + 1] = psi;
    }
}

extern "C" void kernel_launch(void* const* d_in, const int* in_sizes, int n_in,
                              void* d_out, int out_size, void* d_ws, size_t ws_size,
                              hipStream_t stream) {
    const float* X = (const float*)d_in[0];
    const int* S = (const int*)d_in[1];
    const int* RP = (const int*)d_in[2];
    const int* ID = (const int*)d_in[3];
    const int* Seg = (const int*)d_in[4];
    const int* bid = (const int*)d_in[5];
    const float* res_embed = (const float*)d_in[6];
    const float* id_embed = (const float*)d_in[7];
    // k_neighbors (d_in[8]) is a device scalar; problem instance is fixed: k=10, E=64

    const int N = in_sizes[1];  // 3000
    const int E = 64;
    const int K = 10;

    float* out = (float*)d_out;
    float* H = out;                                // N*2E
    float* e0 = H + (size_t)N * 2 * E;             // N*K
    float* e1 = e0 + (size_t)N * K;                // N*K
    float* attr = e1 + (size_t)N * K;              // N*K*2
    float* validp = attr + (size_t)N * K * 2;      // N*K

    int total = N * 2 * E;
    hipLaunchKernelGGL(node_feat_kernel, dim3((total + 255) / 256), dim3(256), 0, stream,
                       res_embed, id_embed, S, RP, ID, H, N, E);
    hipLaunchKernelGGL(knn_kernel, dim3(N), dim3(BLOCK_KNN), 0, stream,
                       X, Seg, bid, e0, e1, attr, validp, N, K);
}

// Round 2
// 103.955 us; speedup vs baseline: 1.2089x; 1.2089x over previous
//
#include <hip/hip_runtime.h>
#include <math.h>

#define TOPK 10
#define WAVE 64

// ---------- small vector helpers ----------
__device__ __forceinline__ void cross3(const float* a, const float* b, float* o) {
    o[0] = a[1] * b[2] - a[2] * b[1];
    o[1] = a[2] * b[0] - a[0] * b[2];
    o[2] = a[0] * b[1] - a[1] * b[0];
}
__device__ __forceinline__ float dot3(const float* a, const float* b) {
    return a[0] * b[0] + a[1] * b[1] + a[2] * b[2];
}

// signed dihedral of 4 points, matches reference formula
__device__ float dihedral4(const float* a, const float* b, const float* c, const float* d) {
    float u1[3], u2[3], u3[3];
    #pragma unroll
    for (int t = 0; t < 3; t++) {
        u1[t] = b[t] - a[t];
        u2[t] = c[t] - b[t];
        u3[t] = d[t] - c[t];
    }
    float n1[3], n2[3];
    cross3(u1, u2, n1);
    cross3(u2, u3, n2);
    float nrm = sqrtf(dot3(u2, u2)) + 1e-12f;
    float u2n[3] = {u2[0] / nrm, u2[1] / nrm, u2[2] / nrm};
    float m[3];
    cross3(n1, u2n, m);
    float x = dot3(n1, n2);
    float y = dot3(m, n2);
    return atan2f(y, x);
}

// ---------- Kernel 1: node features H = [res_embed[S], sinusoid(RP)+id_embed[ID]] ----------
__global__ void node_feat_kernel(const float* __restrict__ res_embed,  // [NUM_AA, E]
                                 const float* __restrict__ id_embed,   // [NUM_ID, E]
                                 const int* __restrict__ S,
                                 const int* __restrict__ RP,
                                 const int* __restrict__ ID,
                                 float* __restrict__ H,  // [N, 2E]
                                 int N, int E) {
    int idx = blockIdx.x * blockDim.x + threadIdx.x;
    int total = N * 2 * E;
    if (idx >= total) return;
    int n = idx / (2 * E);
    int e = idx - n * (2 * E);
    float v;
    if (e < E) {
        v = res_embed[S[n] * E + e];
    } else {
        int j = e - E;
        int half = j >> 1;
        float freq = powf(10000.0f, -2.0f * (float)half / (float)E);
        float ang = (float)RP[n] * freq;
        float sc = (j & 1) ? cosf(ang) : sinf(ang);
        v = sc + id_embed[ID[n] * E + j];
    }
    H[idx] = v;
}

// ---------- Kernel 2: one wave per row; register top-K, shuffle merge, no LDS/barriers ----
__global__ __launch_bounds__(WAVE) void knn_wave_kernel(
    const float* __restrict__ X,    // [N, 4, 3]
    const int* __restrict__ Seg,
    const int* __restrict__ bid,
    float* __restrict__ out_e0,     // [N*K]  dst (neighbor) or -1, as float
    float* __restrict__ out_e1,     // [N*K]  src (row) or -1, as float
    float* __restrict__ out_attr,   // [N*K, 2] (phi, psi)
    float* __restrict__ out_valid,  // [N*K]  1/0
    int N) {
    const int i = blockIdx.x;
    const int lane = threadIdx.x;

    // row-i atoms + squared norms (expanded-form distance matches reference EXACTLY
    // -- do not change this arithmetic; rank order near ties depends on it)
    float xi[4][3], sqi[4];
    #pragma unroll
    for (int c = 0; c < 4; c++) {
        xi[c][0] = X[(i * 4 + c) * 3 + 0];
        xi[c][1] = X[(i * 4 + c) * 3 + 1];
        xi[c][2] = X[(i * 4 + c) * 3 + 2];
        sqi[c] = xi[c][0] * xi[c][0] + xi[c][1] * xi[c][1] + xi[c][2] * xi[c][2];
    }
    const int bi = bid[i];
    const int si = Seg[i];

    const unsigned long long EMPTY = ~0ull;
    // invalid entries carry dist=1e10 exactly, preserving reference pad semantics
    const unsigned long long INV_HI = ((unsigned long long)__float_as_uint(1e10f)) << 32;

    unsigned long long best[TOPK];
    #pragma unroll
    for (int t = 0; t < TOPK; t++) best[t] = EMPTY;
    unsigned long long curmax = EMPTY;

    for (int j = lane; j < N; j += WAVE) {
        unsigned long long key;
        if (bid[j] == bi && Seg[j] == si) {
            float xj[4][3], sqj[4];
            #pragma unroll
            for (int c = 0; c < 4; c++) {
                xj[c][0] = X[(j * 4 + c) * 3 + 0];
                xj[c][1] = X[(j * 4 + c) * 3 + 1];
                xj[c][2] = X[(j * 4 + c) * 3 + 2];
                sqj[c] = xj[c][0] * xj[c][0] + xj[c][1] * xj[c][1] + xj[c][2] * xj[c][2];
            }
            float bestd2 = 3.4e38f;
            #pragma unroll
            for (int c = 0; c < 4; c++) {
                #pragma unroll
                for (int e = 0; e < 4; e++) {
                    float dp = xi[c][0] * xj[e][0] + xi[c][1] * xj[e][1] + xi[c][2] * xj[e][2];
                    float d2 = (sqi[c] + sqj[e]) - 2.0f * dp;
                    bestd2 = fminf(bestd2, d2);
                }
            }
            float dist = sqrtf(fmaxf(bestd2, 0.0f));
            key = ((unsigned long long)__float_as_uint(dist) << 32) | (unsigned)j;
        } else {
            key = INV_HI | (unsigned)j;
        }
        // maintain private top-K (smallest keys); keys are unique (index embedded)
        if (key < curmax) {
            bool done = false;
            #pragma unroll
            for (int t = 0; t < TOPK; t++) {
                bool hit = (!done) && (best[t] == curmax);
                if (hit) { best[t] = key; done = true; }
            }
            curmax = best[0];
            #pragma unroll
            for (int t = 1; t < TOPK; t++) curmax = (best[t] > curmax) ? best[t] : curmax;
        }
    }

    // merge: K global-ascending extractions via wave butterfly (no LDS, no barriers)
    unsigned long long mywin = EMPTY;
    for (int t = 0; t < TOPK; t++) {
        unsigned long long m = best[0];
        #pragma unroll
        for (int u = 1; u < TOPK; u++) m = (best[u] < m) ? best[u] : m;
        #pragma unroll
        for (int off = 32; off > 0; off >>= 1) {
            unsigned long long o = __shfl_xor(m, off, WAVE);
            m = (o < m) ? o : m;
        }
        if (lane == t) mywin = m;
        // consume winner (unique key -> exactly one entry matches)
        #pragma unroll
        for (int u = 0; u < TOPK; u++) {
            if (best[u] == m) best[u] = EMPTY;
        }
    }

    // emit edges + dihedrals (lanes 0..K-1)
    if (lane < TOPK) {
        float dist = __uint_as_float((unsigned)(mywin >> 32));
        int j = (int)(mywin & 0xffffffffu);
        bool valid = (mywin != EMPTY) && (dist < 1e10f);
        int e = i * TOPK + lane;

        out_e0[e] = valid ? (float)j : -1.0f;
        out_e1[e] = valid ? (float)i : -1.0f;
        out_valid[e] = valid ? 1.0f : 0.0f;

        float phi = 0.0f, psi = 0.0f;
        if (valid) {
            float xj[4][3];
            #pragma unroll
            for (int c = 0; c < 4; c++) {
                xj[c][0] = X[(j * 4 + c) * 3 + 0];
                xj[c][1] = X[(j * 4 + c) * 3 + 1];
                xj[c][2] = X[(j * 4 + c) * 3 + 2];
            }
            // phi: C_j, N_i, CA_i, C_i   (dst = neighbor j, src = row i)
            phi = dihedral4(xj[2], xi[0], xi[1], xi[2]);
            // psi: N_j, CA_j, C_j, N_i
            psi = dihedral4(xj[0], xj[1], xj[2], xi[0]);
        }
        out_attr[e * 2 + 0] = phi;
        out_attr[e * 2 + 1] = psi;
    }
}

extern "C" void kernel_launch(void* const* d_in, const int* in_sizes, int n_in,
                              void* d_out, int out_size, void* d_ws, size_t ws_size,
                              hipStream_t stream) {
    const float* X = (const float*)d_in[0];
    const int* S = (const int*)d_in[1];
    const int* RP = (const int*)d_in[2];
    const int* ID = (const int*)d_in[3];
    const int* Seg = (const int*)d_in[4];
    const int* bid = (const int*)d_in[5];
    const float* res_embed = (const float*)d_in[6];
    const float* id_embed = (const float*)d_in[7];
    // k_neighbors (d_in[8]) is a device scalar; problem instance fixed: k=10, E=64

    const int N = in_sizes[1];  // 3000
    const int E = 64;

    float* out = (float*)d_out;
    float* H = out;                                // N*2E
    float* e0 = H + (size_t)N * 2 * E;             // N*K
    float* e1 = e0 + (size_t)N * TOPK;             // N*K
    float* attr = e1 + (size_t)N * TOPK;           // N*K*2
    float* validp = attr + (size_t)N * TOPK * 2;   // N*K

    int total = N * 2 * E;
    hipLaunchKernelGGL(node_feat_kernel, dim3((total + 255) / 256), dim3(256), 0, stream,
                       res_embed, id_embed, S, RP, ID, H, N, E);
    hipLaunchKernelGGL(knn_wave_kernel, dim3(N), dim3(WAVE), 0, stream,
                       X, Seg, bid, e0, e1, attr, validp, N);
}

// Round 3
// 98.414 us; speedup vs baseline: 1.2769x; 1.0563x over previous
//
#include <hip/hip_runtime.h>
#include <math.h>

#define TOPK 10
#define WAVE 64
#define MAX_N 3072   // compacted-candidate LDS capacity; N=3000 here

// ---------- small vector helpers ----------
__device__ __forceinline__ void cross3(const float* a, const float* b, float* o) {
    o[0] = a[1] * b[2] - a[2] * b[1];
    o[1] = a[2] * b[0] - a[0] * b[2];
    o[2] = a[0] * b[1] - a[1] * b[0];
}
__device__ __forceinline__ float dot3(const float* a, const float* b) {
    return a[0] * b[0] + a[1] * b[1] + a[2] * b[2];
}

// signed dihedral of 4 points, matches reference formula
__device__ float dihedral4(const float* a, const float* b, const float* c, const float* d) {
    float u1[3], u2[3], u3[3];
    #pragma unroll
    for (int t = 0; t < 3; t++) {
        u1[t] = b[t] - a[t];
        u2[t] = c[t] - b[t];
        u3[t] = d[t] - c[t];
    }
    float n1[3], n2[3];
    cross3(u1, u2, n1);
    cross3(u2, u3, n2);
    float nrm = sqrtf(dot3(u2, u2)) + 1e-12f;
    float u2n[3] = {u2[0] / nrm, u2[1] / nrm, u2[2] / nrm};
    float m[3];
    cross3(n1, u2n, m);
    float x = dot3(n1, n2);
    float y = dot3(m, n2);
    return atan2f(y, x);
}

// ---------- Kernel 1: node features H = [res_embed[S], sinusoid(RP)+id_embed[ID]] ----------
// one thread per (n, e) for the res half; threads with e < E/2 also produce one
// sin/cos PAIR (same powf/sinf/cosf calls as before -> bit-identical output)
__global__ void node_feat_kernel(const float* __restrict__ res_embed,  // [NUM_AA, E]
                                 const float* __restrict__ id_embed,   // [NUM_ID, E]
                                 const int* __restrict__ S,
                                 const int* __restrict__ RP,
                                 const int* __restrict__ ID,
                                 float* __restrict__ H,  // [N, 2E]
                                 int N, int E) {
    int idx = blockIdx.x * blockDim.x + threadIdx.x;
    if (idx >= N * E) return;
    int n = idx / E;
    int e = idx - n * E;
    float* Hrow = H + (size_t)n * 2 * E;
    Hrow[e] = res_embed[S[n] * E + e];
    if (e < E / 2) {
        int half = e;
        float freq = powf(10000.0f, -2.0f * (float)half / (float)E);
        float ang = (float)RP[n] * freq;
        const float* idrow = id_embed + ID[n] * E;
        Hrow[E + 2 * half + 0] = sinf(ang) + idrow[2 * half + 0];
        Hrow[E + 2 * half + 1] = cosf(ang) + idrow[2 * half + 1];
    }
}

// ---------- Kernel 2: one wave per row; LDS-compacted candidates, dense distance pass ----
__global__ __launch_bounds__(WAVE) void knn_wave_kernel(
    const float* __restrict__ X,    // [N, 4, 3]
    const int* __restrict__ Seg,
    const int* __restrict__ bid,
    float* __restrict__ out_e0,     // [N*K]  dst (neighbor) or -1, as float
    float* __restrict__ out_e1,     // [N*K]  src (row) or -1, as float
    float* __restrict__ out_attr,   // [N*K, 2] (phi, psi)
    float* __restrict__ out_valid,  // [N*K]  1/0
    int N) {
    __shared__ int cand[MAX_N];

    const int i = blockIdx.x;
    const int lane = threadIdx.x;

    // row-i atoms + squared norms (expanded-form distance matches reference EXACTLY
    // -- do not change this arithmetic; rank order near ties depends on it)
    float xi[4][3], sqi[4];
    #pragma unroll
    for (int c = 0; c < 4; c++) {
        xi[c][0] = X[(i * 4 + c) * 3 + 0];
        xi[c][1] = X[(i * 4 + c) * 3 + 1];
        xi[c][2] = X[(i * 4 + c) * 3 + 2];
        sqi[c] = xi[c][0] * xi[c][0] + xi[c][1] * xi[c][1] + xi[c][2] * xi[c][2];
    }
    const int bi = bid[i];
    const int si = Seg[i];

    // ---- phase 1: compact matching candidate indices into LDS (order-preserving) ----
    int count = 0;  // wave-uniform
    for (int j = lane; j < N; j += WAVE) {
        bool ok = (bid[j] == bi) && (Seg[j] == si);
        unsigned long long mask = __ballot(ok);
        if (ok) {
            int pos = count + __popcll(mask & ((1ull << lane) - 1ull));
            cand[pos] = j;
        }
        count += (int)__popcll(mask);
    }
    __syncthreads();  // single wave: compiles to a cheap waitcnt

    // ---- phase 2: dense distance pass over compacted list, private top-K ----
    const unsigned long long EMPTY = ~0ull;
    unsigned long long best[TOPK];
    #pragma unroll
    for (int t = 0; t < TOPK; t++) best[t] = EMPTY;
    unsigned long long curmax = EMPTY;

    for (int t = lane; t < count; t += WAVE) {
        int j = cand[t];
        float xj[4][3], sqj[4];
        #pragma unroll
        for (int c = 0; c < 4; c++) {
            xj[c][0] = X[(j * 4 + c) * 3 + 0];
            xj[c][1] = X[(j * 4 + c) * 3 + 1];
            xj[c][2] = X[(j * 4 + c) * 3 + 2];
            sqj[c] = xj[c][0] * xj[c][0] + xj[c][1] * xj[c][1] + xj[c][2] * xj[c][2];
        }
        float bestd2 = 3.4e38f;
        #pragma unroll
        for (int c = 0; c < 4; c++) {
            #pragma unroll
            for (int e = 0; e < 4; e++) {
                float dp = xi[c][0] * xj[e][0] + xi[c][1] * xj[e][1] + xi[c][2] * xj[e][2];
                float d2 = (sqi[c] + sqj[e]) - 2.0f * dp;
                bestd2 = fminf(bestd2, d2);
            }
        }
        float dist = sqrtf(fmaxf(bestd2, 0.0f));
        unsigned long long key =
            ((unsigned long long)__float_as_uint(dist) << 32) | (unsigned)j;

        // maintain private top-K (smallest keys); keys unique (index embedded)
        if (key < curmax) {
            bool done = false;
            #pragma unroll
            for (int u = 0; u < TOPK; u++) {
                bool hit = (!done) && (best[u] == curmax);
                if (hit) { best[u] = key; done = true; }
            }
            curmax = best[0];
            #pragma unroll
            for (int u = 1; u < TOPK; u++) curmax = (best[u] > curmax) ? best[u] : curmax;
        }
    }

    // ---- merge: K ascending extractions via wave butterfly (no barriers) ----
    unsigned long long mywin = EMPTY;
    for (int t = 0; t < TOPK; t++) {
        unsigned long long m = best[0];
        #pragma unroll
        for (int u = 1; u < TOPK; u++) m = (best[u] < m) ? best[u] : m;
        #pragma unroll
        for (int off = 32; off > 0; off >>= 1) {
            unsigned long long o = __shfl_xor(m, off, WAVE);
            m = (o < m) ? o : m;
        }
        if (lane == t) mywin = m;
        #pragma unroll
        for (int u = 0; u < TOPK; u++) {
            if (best[u] == m) best[u] = EMPTY;
        }
    }

    // ---- emit edges + dihedrals (lanes 0..K-1); pad slots -> -1/0/0 like reference ----
    if (lane < TOPK) {
        int j = (int)(mywin & 0xffffffffu);
        bool valid = (mywin != EMPTY);
        int e = i * TOPK + lane;

        out_e0[e] = valid ? (float)j : -1.0f;
        out_e1[e] = valid ? (float)i : -1.0f;
        out_valid[e] = valid ? 1.0f : 0.0f;

        float phi = 0.0f, psi = 0.0f;
        if (valid) {
            float xj[4][3];
            #pragma unroll
            for (int c = 0; c < 4; c++) {
                xj[c][0] = X[(j * 4 + c) * 3 + 0];
                xj[c][1] = X[(j * 4 + c) * 3 + 1];
                xj[c][2] = X[(j * 4 + c) * 3 + 2];
            }
            // phi: C_j, N_i, CA_i, C_i   (dst = neighbor j, src = row i)
            phi = dihedral4(xj[2], xi[0], xi[1], xi[2]);
            // psi: N_j, CA_j, C_j, N_i
            psi = dihedral4(xj[0], xj[1], xj[2], xi[0]);
        }
        out_attr[e * 2 + 0] = phi;
        out_attr[e * 2 + 1] = psi;
    }
}

extern "C" void kernel_launch(void* const* d_in, const int* in_sizes, int n_in,
                              void* d_out, int out_size, void* d_ws, size_t ws_size,
                              hipStream_t stream) {
    const float* X = (const float*)d_in[0];
    const int* S = (const int*)d_in[1];
    const int* RP = (const int*)d_in[2];
    const int* ID = (const int*)d_in[3];
    const int* Seg = (const int*)d_in[4];
    const int* bid = (const int*)d_in[5];
    const float* res_embed = (const float*)d_in[6];
    const float* id_embed = (const float*)d_in[7];
    // k_neighbors (d_in[8]) is a device scalar; problem instance fixed: k=10, E=64

    const int N = in_sizes[1];  // 3000
    const int E = 64;

    float* out = (float*)d_out;
    float* H = out;                                // N*2E
    float* e0 = H + (size_t)N * 2 * E;             // N*K
    float* e1 = e0 + (size_t)N * TOPK;             // N*K
    float* attr = e1 + (size_t)N * TOPK;           // N*K*2
    float* validp = attr + (size_t)N * TOPK * 2;   // N*K

    int total = N * E;
    hipLaunchKernelGGL(node_feat_kernel, dim3((total + 255) / 256), dim3(256), 0, stream,
                       res_embed, id_embed, S, RP, ID, H, N, E);
    hipLaunchKernelGGL(knn_wave_kernel, dim3(N), dim3(WAVE), 0, stream,
                       X, Seg, bid, e0, e1, attr, validp, N);
}